// Round 1
// baseline (379.740 us; speedup 1.0000x reference)
//
#include <hip/hip_runtime.h>

#define N_NODES 50000
#define D_FEAT 64
#define N_NNZ 800000
#define N_ENT 65536   // 2 * 32768 edge endpoints

// ---------------------------------------------------------------------------
// 1) CSR row pointers from sorted adj_row via per-row binary search
// ---------------------------------------------------------------------------
__global__ void build_rowptr(const int* __restrict__ adj_row,
                             int* __restrict__ row_ptr, int nnz, int n) {
    int r = blockIdx.x * blockDim.x + threadIdx.x;
    if (r > n) return;
    int lo = 0, hi = nnz;           // first idx with adj_row[idx] >= r
    while (lo < hi) {
        int mid = (lo + hi) >> 1;
        if (adj_row[mid] < r) lo = mid + 1; else hi = mid;
    }
    row_ptr[r] = lo;
}

// ---------------------------------------------------------------------------
// 2) y1 = degrev * spmm(x3). x3 blocks are x scaled per-source-node, so we
//    gather only x[c] (256B) + deg[c] and form the three sums in-register.
//    One wave per row; lane t = feature t.
// ---------------------------------------------------------------------------
__global__ __launch_bounds__(256) void spmm1_kernel(
    const float* __restrict__ x, const float* __restrict__ deg,
    const int* __restrict__ adj_col, const int* __restrict__ row_ptr,
    float* __restrict__ y1, int n) {
    int wave = threadIdx.x >> 6;
    int t    = threadIdx.x & 63;
    int r    = blockIdx.x * 4 + wave;
    if (r >= n) return;

    int s = row_ptr[r], e = row_ptr[r + 1];
    float a0 = 0.f, a1 = 0.f, a2 = 0.f;
    for (int i = s; i < e; ++i) {
        int c    = adj_col[i];
        float xv = x[c * D_FEAT + t];
        float dc = deg[c];                 // same addr across wave -> broadcast
        float sq = sqrtf(dc);
        float rs = 1.0f / sq;
        a0 += xv;
        a1 += xv * rs;
        a2 += xv * sq;
    }
    float dr = 1.0f / deg[r];
    float* yr = y1 + (size_t)r * 192;
    yr[t]       = dr * a0;
    yr[64 + t]  = dr * a1;
    yr[128 + t] = dr * a2;
}

// ---------------------------------------------------------------------------
// 3) y2 = degrev * spmm(y1) - x3   (Chebyshev-like recurrence, hop 2)
// ---------------------------------------------------------------------------
__global__ __launch_bounds__(256) void spmm2_kernel(
    const float* __restrict__ x, const float* __restrict__ deg,
    const int* __restrict__ adj_col, const int* __restrict__ row_ptr,
    const float* __restrict__ y1, float* __restrict__ y2, int n) {
    int wave = threadIdx.x >> 6;
    int t    = threadIdx.x & 63;
    int r    = blockIdx.x * 4 + wave;
    if (r >= n) return;

    int s = row_ptr[r], e = row_ptr[r + 1];
    float a0 = 0.f, a1 = 0.f, a2 = 0.f;
    for (int i = s; i < e; ++i) {
        int c = adj_col[i];
        const float* yc = y1 + (size_t)c * 192;
        a0 += yc[t];
        a1 += yc[64 + t];
        a2 += yc[128 + t];
    }
    float dv = deg[r];
    float dr = 1.0f / dv;
    float sq = sqrtf(dv);
    float rs = 1.0f / sq;
    float xv = x[r * D_FEAT + t];
    float* yr = y2 + (size_t)r * 192;
    yr[t]       = dr * a0 - xv;
    yr[64 + t]  = dr * a1 - xv * rs;
    yr[128 + t] = dr * a2 - xv * sq;
}

// ---------------------------------------------------------------------------
// 4) Output gather + [64,9] transpose through LDS.
//    out[ent, d, g]: g 0..2 = x*{1,rsqrt,sqrt}(deg), g 3..5 = y1, g 6..8 = y2.
//    One wave per edge endpoint; 4 endpoints per 256-thread block.
//    N_ENT divides exactly by 4, so no partial blocks (safe __syncthreads).
// ---------------------------------------------------------------------------
__global__ __launch_bounds__(256) void gather_kernel(
    const float* __restrict__ x, const float* __restrict__ deg,
    const int* __restrict__ edge, const float* __restrict__ y1,
    const float* __restrict__ y2, float* __restrict__ out) {
    __shared__ float lds[4][576];
    int wave = threadIdx.x >> 6;
    int t    = threadIdx.x & 63;
    int ent  = blockIdx.x * 4 + wave;

    int n = edge[ent];
    float dv = deg[n];
    float sq = sqrtf(dv);
    float rs = 1.0f / sq;
    float xv = x[n * D_FEAT + t];
    const float* y1n = y1 + (size_t)n * 192;
    const float* y2n = y2 + (size_t)n * 192;

    float h[9];
    h[0] = xv;          h[1] = xv * rs;     h[2] = xv * sq;
    h[3] = y1n[t];      h[4] = y1n[64 + t]; h[5] = y1n[128 + t];
    h[6] = y2n[t];      h[7] = y2n[64 + t]; h[8] = y2n[128 + t];

#pragma unroll
    for (int g = 0; g < 9; ++g) lds[wave][t * 9 + g] = h[g];  // 2-way alias: free
    __syncthreads();

    float* o = out + (size_t)ent * 576;
#pragma unroll
    for (int i = 0; i < 9; ++i) o[i * 64 + t] = lds[wave][i * 64 + t];
}

// ---------------------------------------------------------------------------
extern "C" void kernel_launch(void* const* d_in, const int* in_sizes, int n_in,
                              void* d_out, int out_size, void* d_ws, size_t ws_size,
                              hipStream_t stream) {
    const float* x       = (const float*)d_in[0];   // [N, 64]
    const float* deg     = (const float*)d_in[1];   // [N, 1]
    const int*   adj_row = (const int*)d_in[2];     // [nnz] sorted
    const int*   adj_col = (const int*)d_in[3];     // [nnz]
    const int*   edge    = (const int*)d_in[4];     // [2, 32768]
    float* out = (float*)d_out;

    // Workspace layout (rewritten fully every call):
    //   row_ptr : (N+1) int
    //   y1      : N*192 float
    //   y2      : N*192 float
    char* ws = (char*)d_ws;
    int*   row_ptr = (int*)ws;                      size_t off = ((size_t)(N_NODES + 1) * 4 + 255) & ~(size_t)255;
    float* y1      = (float*)(ws + off);            off += (size_t)N_NODES * 192 * 4;
    float* y2      = (float*)(ws + off);

    build_rowptr<<<(N_NODES + 1 + 255) / 256, 256, 0, stream>>>(adj_row, row_ptr, N_NNZ, N_NODES);
    spmm1_kernel<<<(N_NODES + 3) / 4, 256, 0, stream>>>(x, deg, adj_col, row_ptr, y1, N_NODES);
    spmm2_kernel<<<(N_NODES + 3) / 4, 256, 0, stream>>>(x, deg, adj_col, row_ptr, y1, y2, N_NODES);
    gather_kernel<<<N_ENT / 4, 256, 0, stream>>>(x, deg, edge, y1, y2, out);
}

// Round 2
// 310.612 us; speedup vs baseline: 1.2226x; 1.2226x over previous
//
#include <hip/hip_runtime.h>

#define N_NODES 50000
#define D_FEAT 64
#define N_NNZ 800000
#define N_ENT 65536   // 2 * 32768 edge endpoints

// ---------------------------------------------------------------------------
// 1) CSR row pointers (binary search over sorted adj_row) + per-node scalars
//    scal[n] = {1/deg, rsqrt(deg), sqrt(deg), 0}
// ---------------------------------------------------------------------------
__global__ void build_rowptr_scal(const int* __restrict__ adj_row,
                                  const float* __restrict__ deg,
                                  int* __restrict__ row_ptr,
                                  float4* __restrict__ scal,
                                  int nnz, int n) {
    int r = blockIdx.x * blockDim.x + threadIdx.x;
    if (r > n) return;
    int lo = 0, hi = nnz;           // first idx with adj_row[idx] >= r
    while (lo < hi) {
        int mid = (lo + hi) >> 1;
        if (adj_row[mid] < r) lo = mid + 1; else hi = mid;
    }
    row_ptr[r] = lo;
    if (r < n) {
        float d  = deg[r];
        float sq = sqrtf(d);
        scal[r] = make_float4(1.0f / d, 1.0f / sq, sq, 0.0f);
    }
}

// ---------------------------------------------------------------------------
// 2) y1 = degrev * spmm(x3).  x3 groups are x scaled per-SOURCE-node, so we
//    gather only x[c] + scal[c] and form all three sums in-register.
//    Wave = row. 16-lane group (sub) = neighbor, lane f loads float4 of
//    features: 4 neighbors × 1KB per iteration. Butterfly-reduce at the end.
// ---------------------------------------------------------------------------
__global__ __launch_bounds__(256) void spmm1_kernel(
    const float4* __restrict__ x4, const float4* __restrict__ scal,
    const int* __restrict__ adj_col, const int* __restrict__ row_ptr,
    float4* __restrict__ y1, int n) {
    int wave = threadIdx.x >> 6;
    int t    = threadIdx.x & 63;
    int sub  = t >> 4;      // neighbor slot 0..3
    int f    = t & 15;      // float4 feature block 0..15
    int r    = blockIdx.x * 4 + wave;
    if (r >= n) return;

    int s = row_ptr[r], e = row_ptr[r + 1];
    int cnt = e - s;
    float4 a0 = make_float4(0.f, 0.f, 0.f, 0.f), a1 = a0, a2 = a0;

    int nfull = cnt & ~3;
#pragma unroll 2
    for (int i = 0; i < nfull; i += 4) {
        int c = adj_col[s + i + sub];
        float4 sc = scal[c];
        float4 xv = x4[(size_t)c * 16 + f];
        a0.x += xv.x;        a0.y += xv.y;        a0.z += xv.z;        a0.w += xv.w;
        a1.x += xv.x * sc.y; a1.y += xv.y * sc.y; a1.z += xv.z * sc.y; a1.w += xv.w * sc.y;
        a2.x += xv.x * sc.z; a2.y += xv.y * sc.z; a2.z += xv.z * sc.z; a2.w += xv.w * sc.z;
    }
    if (nfull + sub < cnt) {
        int c = adj_col[s + nfull + sub];
        float4 sc = scal[c];
        float4 xv = x4[(size_t)c * 16 + f];
        a0.x += xv.x;        a0.y += xv.y;        a0.z += xv.z;        a0.w += xv.w;
        a1.x += xv.x * sc.y; a1.y += xv.y * sc.y; a1.z += xv.z * sc.y; a1.w += xv.w * sc.y;
        a2.x += xv.x * sc.z; a2.y += xv.y * sc.z; a2.z += xv.z * sc.z; a2.w += xv.w * sc.z;
    }

    // reduce across the 4 neighbor slots (lanes t, t^16, t^32, t^48)
#pragma unroll
    for (int off = 16; off <= 32; off <<= 1) {
        a0.x += __shfl_xor(a0.x, off); a0.y += __shfl_xor(a0.y, off);
        a0.z += __shfl_xor(a0.z, off); a0.w += __shfl_xor(a0.w, off);
        a1.x += __shfl_xor(a1.x, off); a1.y += __shfl_xor(a1.y, off);
        a1.z += __shfl_xor(a1.z, off); a1.w += __shfl_xor(a1.w, off);
        a2.x += __shfl_xor(a2.x, off); a2.y += __shfl_xor(a2.y, off);
        a2.z += __shfl_xor(a2.z, off); a2.w += __shfl_xor(a2.w, off);
    }

    float dr = scal[r].x;
    if (sub < 3) {
        float4 res = (sub == 0) ? a0 : (sub == 1) ? a1 : a2;
        res.x *= dr; res.y *= dr; res.z *= dr; res.w *= dr;
        y1[(size_t)r * 48 + sub * 16 + f] = res;
    }
}

// ---------------------------------------------------------------------------
// 3) y2 = degrev * spmm(y1) - x3.  Full 768B/neighbor gather of y1 rows,
//    same 4-neighbor float4 structure (3KB per wave per iteration).
// ---------------------------------------------------------------------------
__global__ __launch_bounds__(256) void spmm2_kernel(
    const float4* __restrict__ x4, const float4* __restrict__ scal,
    const int* __restrict__ adj_col, const int* __restrict__ row_ptr,
    const float4* __restrict__ y1, float4* __restrict__ y2, int n) {
    int wave = threadIdx.x >> 6;
    int t    = threadIdx.x & 63;
    int sub  = t >> 4;
    int f    = t & 15;
    int r    = blockIdx.x * 4 + wave;
    if (r >= n) return;

    int s = row_ptr[r], e = row_ptr[r + 1];
    int cnt = e - s;
    float4 a0 = make_float4(0.f, 0.f, 0.f, 0.f), a1 = a0, a2 = a0;

    int nfull = cnt & ~3;
#pragma unroll 2
    for (int i = 0; i < nfull; i += 4) {
        int c = adj_col[s + i + sub];
        const float4* yc = y1 + (size_t)c * 48;
        float4 b0 = yc[f], b1 = yc[16 + f], b2 = yc[32 + f];
        a0.x += b0.x; a0.y += b0.y; a0.z += b0.z; a0.w += b0.w;
        a1.x += b1.x; a1.y += b1.y; a1.z += b1.z; a1.w += b1.w;
        a2.x += b2.x; a2.y += b2.y; a2.z += b2.z; a2.w += b2.w;
    }
    if (nfull + sub < cnt) {
        int c = adj_col[s + nfull + sub];
        const float4* yc = y1 + (size_t)c * 48;
        float4 b0 = yc[f], b1 = yc[16 + f], b2 = yc[32 + f];
        a0.x += b0.x; a0.y += b0.y; a0.z += b0.z; a0.w += b0.w;
        a1.x += b1.x; a1.y += b1.y; a1.z += b1.z; a1.w += b1.w;
        a2.x += b2.x; a2.y += b2.y; a2.z += b2.z; a2.w += b2.w;
    }

#pragma unroll
    for (int off = 16; off <= 32; off <<= 1) {
        a0.x += __shfl_xor(a0.x, off); a0.y += __shfl_xor(a0.y, off);
        a0.z += __shfl_xor(a0.z, off); a0.w += __shfl_xor(a0.w, off);
        a1.x += __shfl_xor(a1.x, off); a1.y += __shfl_xor(a1.y, off);
        a1.z += __shfl_xor(a1.z, off); a1.w += __shfl_xor(a1.w, off);
        a2.x += __shfl_xor(a2.x, off); a2.y += __shfl_xor(a2.y, off);
        a2.z += __shfl_xor(a2.z, off); a2.w += __shfl_xor(a2.w, off);
    }

    float4 sc = scal[r];                       // {1/d, rsqrt, sqrt, 0}
    float4 xv = x4[(size_t)r * 16 + f];
    if (sub < 3) {
        float4 res = (sub == 0) ? a0 : (sub == 1) ? a1 : a2;
        float w = (sub == 0) ? 1.0f : (sub == 1) ? sc.y : sc.z;
        res.x = sc.x * res.x - xv.x * w;
        res.y = sc.x * res.y - xv.y * w;
        res.z = sc.x * res.z - xv.z * w;
        res.w = sc.x * res.w - xv.w * w;
        y2[(size_t)r * 48 + sub * 16 + f] = res;
    }
}

// ---------------------------------------------------------------------------
// 4) Output gather + [64,9] transpose through LDS; float4 store path.
//    out[ent, d, g]: g 0..2 = x*{1,rsqrt,sqrt}, g 3..5 = y1, g 6..8 = y2.
// ---------------------------------------------------------------------------
__global__ __launch_bounds__(256) void gather_kernel(
    const float* __restrict__ x, const float4* __restrict__ scal,
    const int* __restrict__ edge, const float* __restrict__ y1,
    const float* __restrict__ y2, float* __restrict__ out) {
    __shared__ __align__(16) float lds[4][576];
    int wave = threadIdx.x >> 6;
    int t    = threadIdx.x & 63;
    int ent  = blockIdx.x * 4 + wave;

    int n = edge[ent];
    float4 sc = scal[n];                       // {1/d, rsqrt, sqrt, 0}
    float xv = x[n * D_FEAT + t];
    const float* y1n = y1 + (size_t)n * 192;
    const float* y2n = y2 + (size_t)n * 192;

    float h[9];
    h[0] = xv;          h[1] = xv * sc.y;   h[2] = xv * sc.z;
    h[3] = y1n[t];      h[4] = y1n[64 + t]; h[5] = y1n[128 + t];
    h[6] = y2n[t];      h[7] = y2n[64 + t]; h[8] = y2n[128 + t];

#pragma unroll
    for (int g = 0; g < 9; ++g) lds[wave][t * 9 + g] = h[g];  // 2-way alias: free
    __syncthreads();

    const float4* l4 = (const float4*)lds[wave];
    float4* o4 = (float4*)(out + (size_t)ent * 576);   // 144 float4 per entry
    o4[t]      = l4[t];
    o4[t + 64] = l4[t + 64];
    if (t < 16) o4[t + 128] = l4[t + 128];
}

// ---------------------------------------------------------------------------
extern "C" void kernel_launch(void* const* d_in, const int* in_sizes, int n_in,
                              void* d_out, int out_size, void* d_ws, size_t ws_size,
                              hipStream_t stream) {
    const float* x       = (const float*)d_in[0];   // [N, 64]
    const float* deg     = (const float*)d_in[1];   // [N, 1]
    const int*   adj_row = (const int*)d_in[2];     // [nnz] sorted
    const int*   adj_col = (const int*)d_in[3];     // [nnz]
    const int*   edge    = (const int*)d_in[4];     // [2, 32768]
    float* out = (float*)d_out;

    // Workspace layout (rewritten fully every call):
    //   row_ptr : (N+1) int      scal : N float4
    //   y1      : N*192 float    y2   : N*192 float
    char* ws = (char*)d_ws;
    size_t off = 0;
    int*    row_ptr = (int*)ws;      off = ((size_t)(N_NODES + 1) * 4 + 255) & ~(size_t)255;
    float4* scal    = (float4*)(ws + off); off += (size_t)N_NODES * 16;
    off = (off + 255) & ~(size_t)255;
    float4* y1      = (float4*)(ws + off); off += (size_t)N_NODES * 192 * 4;
    float4* y2      = (float4*)(ws + off);

    const float4* x4 = (const float4*)x;

    build_rowptr_scal<<<(N_NODES + 1 + 255) / 256, 256, 0, stream>>>(
        adj_row, deg, row_ptr, scal, N_NNZ, N_NODES);
    spmm1_kernel<<<(N_NODES + 3) / 4, 256, 0, stream>>>(
        x4, scal, adj_col, row_ptr, y1, N_NODES);
    spmm2_kernel<<<(N_NODES + 3) / 4, 256, 0, stream>>>(
        x4, scal, adj_col, row_ptr, y1, y2, N_NODES);
    gather_kernel<<<N_ENT / 4, 256, 0, stream>>>(
        x, scal, edge, (const float*)y1, (const float*)y2, out);
}

// Round 3
// 296.022 us; speedup vs baseline: 1.2828x; 1.0493x over previous
//
#include <hip/hip_runtime.h>

#define N_NODES 50000
#define D_FEAT 64
#define N_NNZ 800000
#define N_ENT 65536   // 2 * 32768 edge endpoints

typedef unsigned int uint32;
typedef unsigned short ushort16;

// ---- bf16 helpers ---------------------------------------------------------
__device__ __forceinline__ uint32 rne1(float a) {
    uint32 u = __float_as_uint(a);
    return (u + 0x7FFFu + ((u >> 16) & 1u)) >> 16;
}
__device__ __forceinline__ uint32 rne2(float a, float b) {   // pack [a:lo, b:hi]
    return rne1(a) | (rne1(b) << 16);
}
__device__ __forceinline__ float bf_lo(uint32 u) { return __uint_as_float(u << 16); }
__device__ __forceinline__ float bf_hi(uint32 u) { return __uint_as_float(u & 0xFFFF0000u); }
__device__ __forceinline__ void unpack8(const uint4 v, float* f) {
    f[0] = bf_lo(v.x); f[1] = bf_hi(v.x);
    f[2] = bf_lo(v.y); f[3] = bf_hi(v.y);
    f[4] = bf_lo(v.z); f[5] = bf_hi(v.z);
    f[6] = bf_lo(v.w); f[7] = bf_hi(v.w);
}
__device__ __forceinline__ float bf1(ushort16 u) { return __uint_as_float(((uint32)u) << 16); }

// ---------------------------------------------------------------------------
// 1a) CSR row pointers (binary search over sorted adj_row) + per-node scalars
//     scal[n] = {1/deg, rsqrt(deg), sqrt(deg), 0}
// ---------------------------------------------------------------------------
__global__ void build_rowptr_scal(const int* __restrict__ adj_row,
                                  const float* __restrict__ deg,
                                  int* __restrict__ row_ptr,
                                  float4* __restrict__ scal,
                                  int nnz, int n) {
    int r = blockIdx.x * blockDim.x + threadIdx.x;
    if (r > n) return;
    int lo = 0, hi = nnz;           // first idx with adj_row[idx] >= r
    while (lo < hi) {
        int mid = (lo + hi) >> 1;
        if (adj_row[mid] < r) lo = mid + 1; else hi = mid;
    }
    row_ptr[r] = lo;
    if (r < n) {
        float d  = deg[r];
        float sq = sqrtf(d);
        scal[r] = make_float4(1.0f / d, 1.0f / sq, sq, 0.0f);
    }
}

// 1b) x (fp32) -> xh (bf16 pairs). 50000*64/2 = 1.6M uint32.
__global__ __launch_bounds__(256) void pack_x(const float2* __restrict__ x2,
                                              uint32* __restrict__ xh, int npair) {
    int i = blockIdx.x * blockDim.x + threadIdx.x;
    if (i >= npair) return;
    float2 v = x2[i];
    xh[i] = rne2(v.x, v.y);
}

// ---------------------------------------------------------------------------
// 2) y1 = degrev * spmm(x3). x3 groups are x scaled per-SOURCE-node, so we
//    gather only xh[c] (128B bf16) + scal[c]. Wave = row; 8 neighbor slots
//    (sub) x 8 lanes (f); lane loads uint4 = 8 bf16 feats. Butterfly-reduce.
//    y1 stored bf16: row = 192 bf16 = 24 uint4.
// ---------------------------------------------------------------------------
__global__ __launch_bounds__(256) void spmm1_kernel(
    const uint4* __restrict__ xh, const float4* __restrict__ scal,
    const int* __restrict__ adj_col, const int* __restrict__ row_ptr,
    uint4* __restrict__ y1h, int n) {
    int wave = threadIdx.x >> 6;
    int t    = threadIdx.x & 63;
    int sub  = t >> 3;      // neighbor slot 0..7
    int f    = t & 7;       // uint4 feature block (8 feats)
    int r    = blockIdx.x * 4 + wave;
    if (r >= n) return;

    int s = row_ptr[r], e = row_ptr[r + 1];
    int cnt = e - s;
    float acc[3][8];
#pragma unroll
    for (int g = 0; g < 3; ++g)
#pragma unroll
        for (int j = 0; j < 8; ++j) acc[g][j] = 0.f;

    int nfull = cnt & ~7;
    for (int i = 0; i < nfull; i += 8) {
        int c = adj_col[s + i + sub];
        float4 sc = scal[c];
        uint4 xv = xh[(size_t)c * 8 + f];    // x row = 64 bf16 = 8 uint4
        float xf[8]; unpack8(xv, xf);
#pragma unroll
        for (int j = 0; j < 8; ++j) {
            acc[0][j] += xf[j];
            acc[1][j] += xf[j] * sc.y;
            acc[2][j] += xf[j] * sc.z;
        }
    }
    if (nfull + sub < cnt) {
        int c = adj_col[s + nfull + sub];
        float4 sc = scal[c];
        uint4 xv = xh[(size_t)c * 8 + f];
        float xf[8]; unpack8(xv, xf);
#pragma unroll
        for (int j = 0; j < 8; ++j) {
            acc[0][j] += xf[j];
            acc[1][j] += xf[j] * sc.y;
            acc[2][j] += xf[j] * sc.z;
        }
    }

    // reduce across the 8 neighbor slots (xor 8,16,32)
#pragma unroll
    for (int off = 8; off <= 32; off <<= 1)
#pragma unroll
        for (int g = 0; g < 3; ++g)
#pragma unroll
            for (int j = 0; j < 8; ++j)
                acc[g][j] += __shfl_xor(acc[g][j], off);

    float dr = scal[r].x;
    if (sub < 3) {
        float v[8];
#pragma unroll
        for (int j = 0; j < 8; ++j) v[j] = acc[sub][j] * dr;
        uint4 o = make_uint4(rne2(v[0], v[1]), rne2(v[2], v[3]),
                             rne2(v[4], v[5]), rne2(v[6], v[7]));
        y1h[(size_t)r * 24 + sub * 8 + f] = o;   // y1 row = 192 bf16 = 24 uint4
    }
}

// ---------------------------------------------------------------------------
// 3) y2 = degrev * spmm(y1) - x3. Gathers bf16 y1 rows (384B/neighbor).
// ---------------------------------------------------------------------------
__global__ __launch_bounds__(256) void spmm2_kernel(
    const float4* __restrict__ x4, const float4* __restrict__ scal,
    const int* __restrict__ adj_col, const int* __restrict__ row_ptr,
    const uint4* __restrict__ y1h, uint4* __restrict__ y2h, int n) {
    int wave = threadIdx.x >> 6;
    int t    = threadIdx.x & 63;
    int sub  = t >> 3;
    int f    = t & 7;
    int r    = blockIdx.x * 4 + wave;
    if (r >= n) return;

    int s = row_ptr[r], e = row_ptr[r + 1];
    int cnt = e - s;
    float acc[3][8];
#pragma unroll
    for (int g = 0; g < 3; ++g)
#pragma unroll
        for (int j = 0; j < 8; ++j) acc[g][j] = 0.f;

    int nfull = cnt & ~7;
    for (int i = 0; i < nfull; i += 8) {
        int c = adj_col[s + i + sub];
        const uint4* yc = y1h + (size_t)c * 24;
        uint4 b0 = yc[f], b1 = yc[8 + f], b2 = yc[16 + f];
        float f0[8], f1[8], f2[8];
        unpack8(b0, f0); unpack8(b1, f1); unpack8(b2, f2);
#pragma unroll
        for (int j = 0; j < 8; ++j) {
            acc[0][j] += f0[j]; acc[1][j] += f1[j]; acc[2][j] += f2[j];
        }
    }
    if (nfull + sub < cnt) {
        int c = adj_col[s + nfull + sub];
        const uint4* yc = y1h + (size_t)c * 24;
        uint4 b0 = yc[f], b1 = yc[8 + f], b2 = yc[16 + f];
        float f0[8], f1[8], f2[8];
        unpack8(b0, f0); unpack8(b1, f1); unpack8(b2, f2);
#pragma unroll
        for (int j = 0; j < 8; ++j) {
            acc[0][j] += f0[j]; acc[1][j] += f1[j]; acc[2][j] += f2[j];
        }
    }

#pragma unroll
    for (int off = 8; off <= 32; off <<= 1)
#pragma unroll
        for (int g = 0; g < 3; ++g)
#pragma unroll
            for (int j = 0; j < 8; ++j)
                acc[g][j] += __shfl_xor(acc[g][j], off);

    float4 sc = scal[r];                       // {1/d, rsqrt, sqrt, 0}
    if (sub < 3) {
        float w = (sub == 0) ? 1.0f : (sub == 1) ? sc.y : sc.z;
        float4 xa = x4[(size_t)r * 16 + f * 2];
        float4 xb = x4[(size_t)r * 16 + f * 2 + 1];
        float xr[8] = {xa.x, xa.y, xa.z, xa.w, xb.x, xb.y, xb.z, xb.w};
        float v[8];
#pragma unroll
        for (int j = 0; j < 8; ++j) v[j] = sc.x * acc[sub][j] - xr[j] * w;
        uint4 o = make_uint4(rne2(v[0], v[1]), rne2(v[2], v[3]),
                             rne2(v[4], v[5]), rne2(v[6], v[7]));
        y2h[(size_t)r * 24 + sub * 8 + f] = o;
    }
}

// ---------------------------------------------------------------------------
// 4) Output gather + [64,9] transpose through LDS; float4 store path.
//    out[ent, d, g]: g 0..2 = x*{1,rsqrt,sqrt}, g 3..5 = y1, g 6..8 = y2.
// ---------------------------------------------------------------------------
__global__ __launch_bounds__(256) void gather_kernel(
    const float* __restrict__ x, const float4* __restrict__ scal,
    const int* __restrict__ edge, const ushort16* __restrict__ y1h,
    const ushort16* __restrict__ y2h, float* __restrict__ out) {
    __shared__ __align__(16) float lds[4][576];
    int wave = threadIdx.x >> 6;
    int t    = threadIdx.x & 63;
    int ent  = blockIdx.x * 4 + wave;

    int n = edge[ent];
    float4 sc = scal[n];                       // {1/d, rsqrt, sqrt, 0}
    float xv = x[n * D_FEAT + t];
    const ushort16* y1n = y1h + (size_t)n * 192;
    const ushort16* y2n = y2h + (size_t)n * 192;

    float h[9];
    h[0] = xv;              h[1] = xv * sc.y;       h[2] = xv * sc.z;
    h[3] = bf1(y1n[t]);     h[4] = bf1(y1n[64 + t]); h[5] = bf1(y1n[128 + t]);
    h[6] = bf1(y2n[t]);     h[7] = bf1(y2n[64 + t]); h[8] = bf1(y2n[128 + t]);

#pragma unroll
    for (int g = 0; g < 9; ++g) lds[wave][t * 9 + g] = h[g];  // 2-way alias: free
    __syncthreads();

    const float4* l4 = (const float4*)lds[wave];
    float4* o4 = (float4*)(out + (size_t)ent * 576);   // 144 float4 per entry
    o4[t]      = l4[t];
    o4[t + 64] = l4[t + 64];
    if (t < 16) o4[t + 128] = l4[t + 128];
}

// ---------------------------------------------------------------------------
extern "C" void kernel_launch(void* const* d_in, const int* in_sizes, int n_in,
                              void* d_out, int out_size, void* d_ws, size_t ws_size,
                              hipStream_t stream) {
    const float* x       = (const float*)d_in[0];   // [N, 64]
    const float* deg     = (const float*)d_in[1];   // [N, 1]
    const int*   adj_row = (const int*)d_in[2];     // [nnz] sorted
    const int*   adj_col = (const int*)d_in[3];     // [nnz]
    const int*   edge    = (const int*)d_in[4];     // [2, 32768]
    float* out = (float*)d_out;

    // Workspace (rewritten fully every call):
    //   row_ptr : (N+1) int        scal : N float4
    //   xh      : N*64 bf16        y1h  : N*192 bf16    y2h : N*192 bf16
    char* ws = (char*)d_ws;
    size_t off = 0;
    int*    row_ptr = (int*)ws;            off = ((size_t)(N_NODES + 1) * 4 + 255) & ~(size_t)255;
    float4* scal    = (float4*)(ws + off); off += (size_t)N_NODES * 16;
    uint32* xh      = (uint32*)(ws + off); off += (size_t)N_NODES * 64 * 2;
    off = (off + 255) & ~(size_t)255;
    uint4*  y1h     = (uint4*)(ws + off);  off += (size_t)N_NODES * 192 * 2;
    off = (off + 255) & ~(size_t)255;
    uint4*  y2h     = (uint4*)(ws + off);

    build_rowptr_scal<<<(N_NODES + 1 + 255) / 256, 256, 0, stream>>>(
        adj_row, deg, row_ptr, scal, N_NNZ, N_NODES);
    pack_x<<<(N_NODES * 32 + 255) / 256, 256, 0, stream>>>(
        (const float2*)x, xh, N_NODES * 32);
    spmm1_kernel<<<(N_NODES + 3) / 4, 256, 0, stream>>>(
        (const uint4*)xh, scal, adj_col, row_ptr, y1h, N_NODES);
    spmm2_kernel<<<(N_NODES + 3) / 4, 256, 0, stream>>>(
        (const float4*)x, scal, adj_col, row_ptr, y1h, y2h, N_NODES);
    gather_kernel<<<N_ENT / 4, 256, 0, stream>>>(
        x, scal, edge, (const ushort16*)y1h, (const ushort16*)y2h, out);
}

// Round 4
// 257.774 us; speedup vs baseline: 1.4732x; 1.1484x over previous
//
#include <hip/hip_runtime.h>

#define N_NODES 50000
#define D_FEAT 64
#define N_NNZ 800000
#define N_ENT 65536   // 2 * 32768 edge endpoints

typedef unsigned int uint32;
typedef unsigned short ushort16;

// ---- bf16 helpers ---------------------------------------------------------
__device__ __forceinline__ uint32 rne1(float a) {
    uint32 u = __float_as_uint(a);
    return (u + 0x7FFFu + ((u >> 16) & 1u)) >> 16;
}
__device__ __forceinline__ uint32 rne2(float a, float b) {   // pack [a:lo, b:hi]
    return rne1(a) | (rne1(b) << 16);
}
__device__ __forceinline__ float bf_lo(uint32 u) { return __uint_as_float(u << 16); }
__device__ __forceinline__ float bf_hi(uint32 u) { return __uint_as_float(u & 0xFFFF0000u); }
__device__ __forceinline__ void unpack8(const uint4 v, float* f) {
    f[0] = bf_lo(v.x); f[1] = bf_hi(v.x);
    f[2] = bf_lo(v.y); f[3] = bf_hi(v.y);
    f[4] = bf_lo(v.z); f[5] = bf_hi(v.z);
    f[6] = bf_lo(v.w); f[7] = bf_hi(v.w);
}
__device__ __forceinline__ float bf1(ushort16 u) { return __uint_as_float(((uint32)u) << 16); }

// ---------------------------------------------------------------------------
// 1a) CSR row pointers (binary search over sorted adj_row) + per-node scalars
//     scal[n] = {1/deg, rsqrt(deg), sqrt(deg), 0}
// ---------------------------------------------------------------------------
__global__ void build_rowptr_scal(const int* __restrict__ adj_row,
                                  const float* __restrict__ deg,
                                  int* __restrict__ row_ptr,
                                  float4* __restrict__ scal,
                                  int nnz, int n) {
    int r = blockIdx.x * blockDim.x + threadIdx.x;
    if (r > n) return;
    int lo = 0, hi = nnz;           // first idx with adj_row[idx] >= r
    while (lo < hi) {
        int mid = (lo + hi) >> 1;
        if (adj_row[mid] < r) lo = mid + 1; else hi = mid;
    }
    row_ptr[r] = lo;
    if (r < n) {
        float d  = deg[r];
        float sq = sqrtf(d);
        scal[r] = make_float4(1.0f / d, 1.0f / sq, sq, 0.0f);
    }
}

// 1b) x (fp32) -> xh (bf16 pairs). 50000*64/2 = 1.6M uint32.
__global__ __launch_bounds__(256) void pack_x(const float2* __restrict__ x2,
                                              uint32* __restrict__ xh, int npair) {
    int i = blockIdx.x * blockDim.x + threadIdx.x;
    if (i >= npair) return;
    float2 v = x2[i];
    xh[i] = rne2(v.x, v.y);
}

// ---------------------------------------------------------------------------
// 2) y1 = degrev * spmm(x3). x3 groups are x scaled per-SOURCE-node, so we
//    gather only xh[c] (128B bf16) + scal[c].
//    Layout: wave = 8 rows; 8-lane octet owns one row; lane holds 8 feats
//    (uint4 of bf16). Octet walks its own neighbor list serially (manual
//    2-way unroll for MLP). NO cross-lane reduction. Row = 24 uint4 out.
// ---------------------------------------------------------------------------
__global__ __launch_bounds__(256) void spmm1_kernel(
    const uint4* __restrict__ xh, const float4* __restrict__ scal,
    const int* __restrict__ adj_col, const int* __restrict__ row_ptr,
    uint4* __restrict__ y1h, int n) {
    int t    = threadIdx.x & 63;
    int f    = t & 7;                                  // feature block
    int r    = (blockIdx.x * 4 + (threadIdx.x >> 6)) * 8 + (t >> 3);
    if (r >= n) return;

    int s = row_ptr[r], e = row_ptr[r + 1];
    int cnt = e - s;
    float a0[8], a1[8], a2[8];
#pragma unroll
    for (int j = 0; j < 8; ++j) { a0[j] = 0.f; a1[j] = 0.f; a2[j] = 0.f; }

    int i = 0;
    for (; i + 2 <= cnt; i += 2) {
        int c0 = adj_col[s + i];
        int c1 = adj_col[s + i + 1];
        uint4 xv0 = xh[(size_t)c0 * 8 + f];
        uint4 xv1 = xh[(size_t)c1 * 8 + f];
        float4 sc0 = scal[c0];
        float4 sc1 = scal[c1];
        float xf0[8], xf1[8];
        unpack8(xv0, xf0); unpack8(xv1, xf1);
#pragma unroll
        for (int j = 0; j < 8; ++j) {
            a0[j] += xf0[j];
            a1[j] += xf0[j] * sc0.y;
            a2[j] += xf0[j] * sc0.z;
            a0[j] += xf1[j];
            a1[j] += xf1[j] * sc1.y;
            a2[j] += xf1[j] * sc1.z;
        }
    }
    if (i < cnt) {
        int c = adj_col[s + i];
        uint4 xv = xh[(size_t)c * 8 + f];
        float4 sc = scal[c];
        float xf[8]; unpack8(xv, xf);
#pragma unroll
        for (int j = 0; j < 8; ++j) {
            a0[j] += xf[j];
            a1[j] += xf[j] * sc.y;
            a2[j] += xf[j] * sc.z;
        }
    }

    float dr = scal[r].x;
    uint4* yr = y1h + (size_t)r * 24 + f;
    yr[0]  = make_uint4(rne2(a0[0]*dr, a0[1]*dr), rne2(a0[2]*dr, a0[3]*dr),
                        rne2(a0[4]*dr, a0[5]*dr), rne2(a0[6]*dr, a0[7]*dr));
    yr[8]  = make_uint4(rne2(a1[0]*dr, a1[1]*dr), rne2(a1[2]*dr, a1[3]*dr),
                        rne2(a1[4]*dr, a1[5]*dr), rne2(a1[6]*dr, a1[7]*dr));
    yr[16] = make_uint4(rne2(a2[0]*dr, a2[1]*dr), rne2(a2[2]*dr, a2[3]*dr),
                        rne2(a2[4]*dr, a2[5]*dr), rne2(a2[6]*dr, a2[7]*dr));
}

// ---------------------------------------------------------------------------
// 3) y2 = degrev * spmm(y1) - x3. Gathers bf16 y1 rows (384B/neighbor),
//    same octet-per-row structure, 3 uint4 loads per neighbor.
// ---------------------------------------------------------------------------
__global__ __launch_bounds__(256) void spmm2_kernel(
    const float4* __restrict__ x4, const float4* __restrict__ scal,
    const int* __restrict__ adj_col, const int* __restrict__ row_ptr,
    const uint4* __restrict__ y1h, uint4* __restrict__ y2h, int n) {
    int t    = threadIdx.x & 63;
    int f    = t & 7;
    int r    = (blockIdx.x * 4 + (threadIdx.x >> 6)) * 8 + (t >> 3);
    if (r >= n) return;

    int s = row_ptr[r], e = row_ptr[r + 1];
    int cnt = e - s;
    float a0[8], a1[8], a2[8];
#pragma unroll
    for (int j = 0; j < 8; ++j) { a0[j] = 0.f; a1[j] = 0.f; a2[j] = 0.f; }

    int i = 0;
    for (; i + 2 <= cnt; i += 2) {
        int c0 = adj_col[s + i];
        int c1 = adj_col[s + i + 1];
        const uint4* yc0 = y1h + (size_t)c0 * 24 + f;
        const uint4* yc1 = y1h + (size_t)c1 * 24 + f;
        uint4 b0 = yc0[0], b1 = yc0[8], b2 = yc0[16];
        uint4 d0 = yc1[0], d1 = yc1[8], d2 = yc1[16];
        float f0[8], f1[8], f2[8], g0[8], g1[8], g2[8];
        unpack8(b0, f0); unpack8(b1, f1); unpack8(b2, f2);
        unpack8(d0, g0); unpack8(d1, g1); unpack8(d2, g2);
#pragma unroll
        for (int j = 0; j < 8; ++j) {
            a0[j] += f0[j] + g0[j];
            a1[j] += f1[j] + g1[j];
            a2[j] += f2[j] + g2[j];
        }
    }
    if (i < cnt) {
        int c = adj_col[s + i];
        const uint4* yc = y1h + (size_t)c * 24 + f;
        uint4 b0 = yc[0], b1 = yc[8], b2 = yc[16];
        float f0[8], f1[8], f2[8];
        unpack8(b0, f0); unpack8(b1, f1); unpack8(b2, f2);
#pragma unroll
        for (int j = 0; j < 8; ++j) {
            a0[j] += f0[j]; a1[j] += f1[j]; a2[j] += f2[j];
        }
    }

    float4 sc = scal[r];                       // {1/d, rsqrt, sqrt, 0}
    float4 xa = x4[(size_t)r * 16 + f * 2];
    float4 xb = x4[(size_t)r * 16 + f * 2 + 1];
    float xr[8] = {xa.x, xa.y, xa.z, xa.w, xb.x, xb.y, xb.z, xb.w};
    float v0[8], v1[8], v2[8];
#pragma unroll
    for (int j = 0; j < 8; ++j) {
        v0[j] = sc.x * a0[j] - xr[j];
        v1[j] = sc.x * a1[j] - xr[j] * sc.y;
        v2[j] = sc.x * a2[j] - xr[j] * sc.z;
    }
    uint4* yr = y2h + (size_t)r * 24 + f;
    yr[0]  = make_uint4(rne2(v0[0], v0[1]), rne2(v0[2], v0[3]),
                        rne2(v0[4], v0[5]), rne2(v0[6], v0[7]));
    yr[8]  = make_uint4(rne2(v1[0], v1[1]), rne2(v1[2], v1[3]),
                        rne2(v1[4], v1[5]), rne2(v1[6], v1[7]));
    yr[16] = make_uint4(rne2(v2[0], v2[1]), rne2(v2[2], v2[3]),
                        rne2(v2[4], v2[5]), rne2(v2[6], v2[7]));
}

// ---------------------------------------------------------------------------
// 4) Output gather + [64,9] transpose through LDS; float4 store path.
//    out[ent, d, g]: g 0..2 = x*{1,rsqrt,sqrt}, g 3..5 = y1, g 6..8 = y2.
// ---------------------------------------------------------------------------
__global__ __launch_bounds__(256) void gather_kernel(
    const float* __restrict__ x, const float4* __restrict__ scal,
    const int* __restrict__ edge, const ushort16* __restrict__ y1h,
    const ushort16* __restrict__ y2h, float* __restrict__ out) {
    __shared__ __align__(16) float lds[4][576];
    int wave = threadIdx.x >> 6;
    int t    = threadIdx.x & 63;
    int ent  = blockIdx.x * 4 + wave;

    int n = edge[ent];
    float4 sc = scal[n];                       // {1/d, rsqrt, sqrt, 0}
    float xv = x[n * D_FEAT + t];
    const ushort16* y1n = y1h + (size_t)n * 192;
    const ushort16* y2n = y2h + (size_t)n * 192;

    float h[9];
    h[0] = xv;              h[1] = xv * sc.y;        h[2] = xv * sc.z;
    h[3] = bf1(y1n[t]);     h[4] = bf1(y1n[64 + t]); h[5] = bf1(y1n[128 + t]);
    h[6] = bf1(y2n[t]);     h[7] = bf1(y2n[64 + t]); h[8] = bf1(y2n[128 + t]);

#pragma unroll
    for (int g = 0; g < 9; ++g) lds[wave][t * 9 + g] = h[g];  // 2-way alias: free
    __syncthreads();

    const float4* l4 = (const float4*)lds[wave];
    float4* o4 = (float4*)(out + (size_t)ent * 576);   // 144 float4 per entry
    o4[t]      = l4[t];
    o4[t + 64] = l4[t + 64];
    if (t < 16) o4[t + 128] = l4[t + 128];
}

// ---------------------------------------------------------------------------
extern "C" void kernel_launch(void* const* d_in, const int* in_sizes, int n_in,
                              void* d_out, int out_size, void* d_ws, size_t ws_size,
                              hipStream_t stream) {
    const float* x       = (const float*)d_in[0];   // [N, 64]
    const float* deg     = (const float*)d_in[1];   // [N, 1]
    const int*   adj_row = (const int*)d_in[2];     // [nnz] sorted
    const int*   adj_col = (const int*)d_in[3];     // [nnz]
    const int*   edge    = (const int*)d_in[4];     // [2, 32768]
    float* out = (float*)d_out;

    // Workspace (rewritten fully every call):
    //   row_ptr : (N+1) int        scal : N float4
    //   xh      : N*64 bf16        y1h  : N*192 bf16    y2h : N*192 bf16
    char* ws = (char*)d_ws;
    size_t off = 0;
    int*    row_ptr = (int*)ws;            off = ((size_t)(N_NODES + 1) * 4 + 255) & ~(size_t)255;
    float4* scal    = (float4*)(ws + off); off += (size_t)N_NODES * 16;
    uint32* xh      = (uint32*)(ws + off); off += (size_t)N_NODES * 64 * 2;
    off = (off + 255) & ~(size_t)255;
    uint4*  y1h     = (uint4*)(ws + off);  off += (size_t)N_NODES * 192 * 2;
    off = (off + 255) & ~(size_t)255;
    uint4*  y2h     = (uint4*)(ws + off);

    build_rowptr_scal<<<(N_NODES + 1 + 255) / 256, 256, 0, stream>>>(
        adj_row, deg, row_ptr, scal, N_NNZ, N_NODES);
    pack_x<<<(N_NODES * 32 + 255) / 256, 256, 0, stream>>>(
        (const float2*)x, xh, N_NODES * 32);
    spmm1_kernel<<<(N_NODES + 31) / 32, 256, 0, stream>>>(
        (const uint4*)xh, scal, adj_col, row_ptr, y1h, N_NODES);
    spmm2_kernel<<<(N_NODES + 31) / 32, 256, 0, stream>>>(
        (const float4*)x, scal, adj_col, row_ptr, y1h, y2h, N_NODES);
    gather_kernel<<<N_ENT / 4, 256, 0, stream>>>(
        x, scal, edge, (const ushort16*)y1h, (const ushort16*)y2h, out);
}